// Round 16
// baseline (209.304 us; speedup 1.0000x reference)
//
#include <hip/hip_runtime.h>
#include <cstdint>
#include <cstddef>

// Problem constants (B=2, S=2048, HID=1024, H=16, KVH=4, D=64)
#define S_LEN   2048
#define BATCH   2
#define HID_DIM 1024
#define NHEAD   16
#define NKV     4
#define DHEAD   64
#define SCALE_F 0.125f
#define L2E     1.44269504f
#define QSCALE  (SCALE_F * L2E)          // folded into q at projection time
#define CAPL2   (50.0f * L2E)            // clamp bound in log2 space

typedef unsigned short u16;
typedef __attribute__((ext_vector_type(8))) short  short8_t;  // 8 bf16
typedef __attribute__((ext_vector_type(4))) float  f32x4;
typedef __attribute__((ext_vector_type(4))) u16    u16x4;

static __device__ __forceinline__ u16 f2bf(float f) {
  uint32_t x = __builtin_bit_cast(uint32_t, f);
  x += 0x7fffu + ((x >> 16) & 1u);
  return (u16)(x >> 16);
}

static __device__ __forceinline__ void gload_lds16(const void* g, void* l) {
  __builtin_amdgcn_global_load_lds((const __attribute__((address_space(1))) void*)g,
                                   (__attribute__((address_space(3))) void*)l, 16, 0, 0);
}

// e = 2^(clamp(x, -CAPL2, CAPL2)); the -CAPL2 shift cancels in softmax normalization
static __device__ __forceinline__ float exp2med3(float x) {
  return __builtin_amdgcn_exp2f(__builtin_amdgcn_fmed3f(x, -CAPL2, CAPL2));
}

static __device__ __forceinline__ short8_t pack8(f32x4 a, f32x4 b) {
  short8_t r;
  r[0] = (short)f2bf(a[0]); r[1] = (short)f2bf(a[1]);
  r[2] = (short)f2bf(a[2]); r[3] = (short)f2bf(a[3]);
  r[4] = (short)f2bf(b[0]); r[5] = (short)f2bf(b[1]);
  r[6] = (short)f2bf(b[2]); r[7] = (short)f2bf(b[3]);
  return r;
}

// ---------------------------------------------------------------- fused fp32->bf16 casts
__global__ void cast_all(const float* __restrict__ X,  u16* __restrict__ xb,
                         const float* __restrict__ Wq, u16* __restrict__ wqb,
                         const float* __restrict__ Wk, u16* __restrict__ wkb,
                         const float* __restrict__ Wv, u16* __restrict__ wvb,
                         const float* __restrict__ Wo, u16* __restrict__ wob) {
  const float* src; u16* dst; int n4;
  switch (blockIdx.y) {
    case 0:  src = X;  dst = xb;  n4 = (BATCH * S_LEN * HID_DIM) / 4; break;
    case 1:  src = Wq; dst = wqb; n4 = (HID_DIM * HID_DIM) / 4;       break;
    case 2:  src = Wk; dst = wkb; n4 = (NKV * DHEAD * HID_DIM) / 4;   break;
    case 3:  src = Wv; dst = wvb; n4 = (NKV * DHEAD * HID_DIM) / 4;   break;
    default: src = Wo; dst = wob; n4 = (HID_DIM * HID_DIM) / 4;       break;
  }
  for (int i = blockIdx.x * 256 + threadIdx.x; i < n4; i += gridDim.x * 256) {
    f32x4 v = ((const f32x4*)src)[i];
    u16x4 o;
    o[0] = f2bf(v[0]); o[1] = f2bf(v[1]); o[2] = f2bf(v[2]); o[3] = f2bf(v[3]);
    ((u16x4*)dst)[i] = o;
  }
}

// ---------------------------------------------------------------- fused QKV GEMM + RoPE + V^T
// BM=64, BN=128, BK=64, 4 waves (2x2; wave tile 32x64). Grid (M/64, 12) = 768 blocks.
__global__ __launch_bounds__(256, 4) void gemm_qkv(const u16* __restrict__ Xb,
                                                   const u16* __restrict__ Wqb,
                                                   const u16* __restrict__ Wkb,
                                                   const u16* __restrict__ Wvb,
                                                   const float* __restrict__ bq,
                                                   const float* __restrict__ bk,
                                                   const float* __restrict__ bv,
                                                   const float* __restrict__ cosb,
                                                   const float* __restrict__ sinb,
                                                   u16* __restrict__ qout,
                                                   u16* __restrict__ kout,
                                                   u16* __restrict__ vtout) {
  __shared__ u16 As[64 * 64];
  __shared__ u16 Bs[128 * 64];
  const int tid = threadIdx.x, lane = tid & 63, wid = tid >> 6;
  const int l15 = lane & 15, lg = lane >> 4;
  const int m0 = blockIdx.x * 64, n0 = blockIdx.y * 128;
  const int wm = wid & 1, wn = wid >> 1;
  const int K = HID_DIM;

  const u16* Wp; const float* biasp; int nl, mode;
  if (n0 < 1024)      { Wp = Wqb; biasp = bq; nl = n0;        mode = 0; }
  else if (n0 < 1280) { Wp = Wkb; biasp = bk; nl = n0 - 1024; mode = 1; }
  else                { Wp = Wvb; biasp = bv; nl = n0 - 1280; mode = 2; }

  f32x4 acc[4][2];   // [fn][fm]
  #pragma unroll
  for (int a = 0; a < 4; ++a)
    #pragma unroll
    for (int b2 = 0; b2 < 2; ++b2) acc[a][b2] = (f32x4){0.f, 0.f, 0.f, 0.f};

  const int srow = (lane >> 3), sg = (lane & 7);

  for (int kk = 0; kk < K; kk += 64) {
    __syncthreads();
    #pragma unroll
    for (int i = 0; i < 6; ++i) {              // 24 chunks of 8 rows: 8 A + 16 B
      const int c = wid * 6 + i;
      if (c < 8) {
        const int r = c * 8 + srow;
        const int g = sg ^ (r & 7);
        gload_lds16(Xb + (size_t)(m0 + r) * K + kk + g * 8, As + c * 512);
      } else {
        const int cb = c - 8;
        const int r = cb * 8 + srow;
        const int g = sg ^ (r & 7);
        gload_lds16(Wp + (size_t)(nl + r) * K + kk + g * 8, Bs + cb * 512);
      }
    }
    __syncthreads();
    #pragma unroll
    for (int ks = 0; ks < 2; ++ks) {
      short8_t xa[2], wb[4];
      #pragma unroll
      for (int f = 0; f < 2; ++f) {
        const int rm = wm * 32 + f * 16 + l15;
        xa[f] = *(const short8_t*)(As + rm * 64 + (((ks * 4 + lg) ^ (rm & 7)) * 8));
      }
      #pragma unroll
      for (int f = 0; f < 4; ++f) {
        const int rn = wn * 64 + f * 16 + l15;
        wb[f] = *(const short8_t*)(Bs + rn * 64 + (((ks * 4 + lg) ^ (rn & 7)) * 8));
      }
      if (mode != 2) {
        #pragma unroll
        for (int fn = 0; fn < 4; ++fn)
          #pragma unroll
          for (int fm = 0; fm < 2; ++fm)
            acc[fn][fm] = __builtin_amdgcn_mfma_f32_16x16x32_bf16(wb[fn], xa[fm], acc[fn][fm], 0, 0, 0);
      } else {
        #pragma unroll
        for (int fn = 0; fn < 4; ++fn)
          #pragma unroll
          for (int fm = 0; fm < 2; ++fm)
            acc[fn][fm] = __builtin_amdgcn_mfma_f32_16x16x32_bf16(xa[fm], wb[fn], acc[fn][fm], 0, 0, 0);
      }
    }
  }

  const int m_base = m0 + wm * 32;
  const int nlb = nl + wn * 64;

  if (mode < 2) {
    const int Nout = (mode == 0) ? HID_DIM : (NKV * DHEAD);
    const float qs = (mode == 0) ? QSCALE : 1.0f;
    u16* outb = (mode == 0) ? qout : kout;
    #pragma unroll
    for (int fm = 0; fm < 2; ++fm) {
      const int row = m_base + fm * 16 + l15;
      #pragma unroll
      for (int fn = 0; fn < 2; ++fn) {
        const int dh = fn * 16 + lg * 4;          // in [0,32)
        const f32x4 c4 = *(const f32x4*)(cosb + (size_t)row * 64 + dh);
        const f32x4 s4 = *(const f32x4*)(sinb + (size_t)row * 64 + dh);
        f32x4 x1 = acc[fn][fm]     + *(const f32x4*)(biasp + nlb + fn * 16 + lg * 4);
        f32x4 x2 = acc[fn + 2][fm] + *(const f32x4*)(biasp + nlb + (fn + 2) * 16 + lg * 4);
        f32x4 o1 = (x1 * c4 - x2 * s4) * qs;
        f32x4 o2 = (x2 * c4 + x1 * s4) * qs;
        u16x4 u1, u2;
        #pragma unroll
        for (int i = 0; i < 4; ++i) { u1[i] = f2bf(o1[i]); u2[i] = f2bf(o2[i]); }
        *(u16x4*)(outb + (size_t)row * Nout + nlb + fn * 16 + lg * 4)       = u1;
        *(u16x4*)(outb + (size_t)row * Nout + nlb + (fn + 2) * 16 + lg * 4) = u2;
      }
    }
  } else {
    // acc[fn][fm] holds D[d][s]: d = nlb+fn*16+l15, s = m_base+fm*16+lg*4+i
    #pragma unroll
    for (int fn = 0; fn < 4; ++fn) {
      const int d = nlb + fn * 16 + l15;
      const float bvs = biasp[d];
      #pragma unroll
      for (int fm = 0; fm < 2; ++fm) {
        const int s0 = m_base + fm * 16 + lg * 4;
        const int b_ = s0 >> 11, s_ = s0 & (S_LEN - 1);
        u16x4 o;
        #pragma unroll
        for (int i = 0; i < 4; ++i) o[i] = f2bf(acc[fn][fm][i] + bvs);
        *(u16x4*)(vtout + (size_t)(b_ * 256 + d) * S_LEN + s_) = o;
      }
    }
  }
}

// ---------------------------------------------------------------- out-proj GEMM (fp32 out)
// BM=64, BN=128: grid (64, 8) = 512 blocks.
__global__ __launch_bounds__(256, 4) void gemm_out(const u16* __restrict__ A,
                                                   const u16* __restrict__ W,
                                                   const float* __restrict__ bias,
                                                   float* __restrict__ outp) {
  __shared__ u16 As[64 * 64];
  __shared__ u16 Bs[128 * 64];
  const int tid = threadIdx.x, lane = tid & 63, wid = tid >> 6;
  const int l15 = lane & 15, lg = lane >> 4;
  const int m0 = blockIdx.x * 64, n0 = blockIdx.y * 128;
  const int wm = wid & 1, wn = wid >> 1;
  const int K = HID_DIM, N = HID_DIM;

  f32x4 acc[4][2];
  #pragma unroll
  for (int a = 0; a < 4; ++a)
    #pragma unroll
    for (int b2 = 0; b2 < 2; ++b2) acc[a][b2] = (f32x4){0.f, 0.f, 0.f, 0.f};

  const int srow = (lane >> 3), sg = (lane & 7);

  for (int kk = 0; kk < K; kk += 64) {
    __syncthreads();
    #pragma unroll
    for (int i = 0; i < 6; ++i) {
      const int c = wid * 6 + i;
      if (c < 8) {
        const int r = c * 8 + srow;
        const int g = sg ^ (r & 7);
        gload_lds16(A + (size_t)(m0 + r) * K + kk + g * 8, As + c * 512);
      } else {
        const int cb = c - 8;
        const int r = cb * 8 + srow;
        const int g = sg ^ (r & 7);
        gload_lds16(W + (size_t)(n0 + r) * K + kk + g * 8, Bs + cb * 512);
      }
    }
    __syncthreads();
    #pragma unroll
    for (int ks = 0; ks < 2; ++ks) {
      short8_t xa[2], wb[4];
      #pragma unroll
      for (int f = 0; f < 2; ++f) {
        const int rm = wm * 32 + f * 16 + l15;
        xa[f] = *(const short8_t*)(As + rm * 64 + (((ks * 4 + lg) ^ (rm & 7)) * 8));
      }
      #pragma unroll
      for (int f = 0; f < 4; ++f) {
        const int rn = wn * 64 + f * 16 + l15;
        wb[f] = *(const short8_t*)(Bs + rn * 64 + (((ks * 4 + lg) ^ (rn & 7)) * 8));
      }
      #pragma unroll
      for (int fn = 0; fn < 4; ++fn)
        #pragma unroll
        for (int fm = 0; fm < 2; ++fm)
          acc[fn][fm] = __builtin_amdgcn_mfma_f32_16x16x32_bf16(wb[fn], xa[fm], acc[fn][fm], 0, 0, 0);
    }
  }

  const int m_base = m0 + wm * 32, n_base = n0 + wn * 64;
  #pragma unroll
  for (int fn = 0; fn < 4; ++fn) {
    const int col = n_base + fn * 16 + lg * 4;
    const f32x4 bvv = *(const f32x4*)(bias + col);
    #pragma unroll
    for (int fm = 0; fm < 2; ++fm) {
      const int row = m_base + fm * 16 + l15;
      *(f32x4*)(outp + (size_t)row * N + col) = acc[fn][fm] + bvv;
    }
  }
}

// ---------------------------------------------------------------- fused causal attention
// grid (B*H, S/64), 256 thr (4 waves x 16 q-rows). ONE 40 KB LDS pool, aliased:
//   pass 1: two 16 KB K buffers -> KVBLK=128 (half the barriers/vmcnt waits of R15)
//   pass 2: kS 2x8 KB + vS 8 KB + pF 16 KB (R15 layout: transposed 256B-contiguous stores)
// 40 KB -> 4 blocks/CU. Pass transition fenced by pass-1's final loop barrier.
__global__ __launch_bounds__(256, 4) void attn_fused(const u16* __restrict__ qb,
                                                     const u16* __restrict__ kb,
                                                     const u16* __restrict__ vtb,
                                                     float* __restrict__ attn,
                                                     u16* __restrict__ ctxb) {
  __shared__ __attribute__((aligned(16))) char smem[40960];

  const int tid = threadIdx.x, lane = tid & 63, wid = tid >> 6;
  const int l15 = lane & 15, lg = lane >> 4;
  const int bh = blockIdx.x, b = bh >> 4, h = bh & 15, kvh = h >> 2;
  const int qt = (int)(gridDim.y - 1 - blockIdx.y);   // longest-first
  const int q0 = qt * 64;
  const int NT = qt + 1;
  const int qw = q0 + wid * 16;
  const int qrow = qw + l15;

  const u16* qp = qb + (size_t)(b * S_LEN + qrow) * HID_DIM + h * DHEAD + lg * 8;
  const short8_t qf0 = *(const short8_t*)qp;
  const short8_t qf1 = *(const short8_t*)(qp + 32);

  const u16* kbase  = kb  + (size_t)(b * S_LEN) * (NKV * DHEAD) + kvh * DHEAD;
  const u16* vtbase = vtb + (size_t)(b * NKV + kvh) * DHEAD * S_LEN;

  const int sr8 = wid * 8 + (lane >> 3);   // staging row within 32-row chunk
  const int sgr = lane & 7;

  // ---------------- pass 1: lsum, KVBLK=128 (LDS = two 16 KB K buffers)
  {
    u16* kb0 = (u16*)smem;
    u16* kb1 = (u16*)(smem + 16384);
    const int NT2 = (qt + 2) >> 1;        // ceil((qt+1)*64 / 128)

    auto stageK128 = [&](u16* dst, int kv0) {
      #pragma unroll
      for (int it = 0; it < 4; ++it) {
        const int r = it * 32 + sr8;
        const int g = sgr ^ (r & 7);
        gload_lds16(kbase + (size_t)(kv0 + r) * (NKV * DHEAD) + g * 8,
                    dst + (it * 32 + wid * 8) * 64);
      }
    };

    f32x4 lacc = (f32x4){0.f, 0.f, 0.f, 0.f};
    stageK128(kb0, 0);
    for (int t = 0; t < NT2; ++t) {
      const int kv0 = t * 128;
      if (t + 1 < NT2) {
        stageK128((t & 1) ? kb0 : kb1, kv0 + 128);
        asm volatile("s_waitcnt vmcnt(4)" ::: "memory");
      } else {
        asm volatile("s_waitcnt vmcnt(0)" ::: "memory");
      }
      __builtin_amdgcn_s_barrier();
      const u16* ks = (t & 1) ? kb1 : kb0;
      const bool maskc = (kv0 + 127 > qw);
      #pragma unroll
      for (int g16 = 0; g16 < 8; ++g16) {
        const int r = g16 * 16 + l15;
        short8_t ka0 = *(const short8_t*)(ks + r * 64 + ((lg ^ (r & 7)) * 8));
        short8_t ka1 = *(const short8_t*)(ks + r * 64 + (((4 + lg) ^ (r & 7)) * 8));
        f32x4 sacc = (f32x4){0.f, 0.f, 0.f, 0.f};
        sacc = __builtin_amdgcn_mfma_f32_16x16x32_bf16(ka0, qf0, sacc, 0, 0, 0);
        sacc = __builtin_amdgcn_mfma_f32_16x16x32_bf16(ka1, qf1, sacc, 0, 0, 0);
        #pragma unroll
        for (int i = 0; i < 4; ++i) {
          float e = exp2med3(sacc[i]);
          if (maskc) {
            const int kvi = kv0 + g16 * 16 + lg * 4 + i;
            e = (kvi <= qrow) ? e : 0.f;
          }
          lacc[i] += e;
        }
      }
      __builtin_amdgcn_s_barrier();
    }
    // stash partial in VGPR; reduce below (no LDS use)
    float lsum_ = (lacc[0] + lacc[1]) + (lacc[2] + lacc[3]);
    lsum_ += __shfl_xor(lsum_, 16);
    lsum_ += __shfl_xor(lsum_, 32);
    // fall through with invl in a register
    const float invl = 1.f / lsum_;

    // ---------------- pass 2: QK -> pF (fp32) -> 256B-contiguous stores + PV
    u16* kS2a = (u16*)smem;
    u16* kS2b = (u16*)(smem + 8192);
    u16* vS   = (u16*)(smem + 16384);
    float (*pF)[64] = (float(*)[64])(smem + 24576 + wid * 4096);  // per-wave [16][64]

    auto stageK = [&](u16* dst, int kv0) {
      #pragma unroll
      for (int it = 0; it < 2; ++it) {
        const int r = it * 32 + sr8;
        const int g = sgr ^ (r & 7);
        gload_lds16(kbase + (size_t)(kv0 + r) * (NKV * DHEAD) + g * 8,
                    dst + (it * 32 + wid * 8) * 64);
      }
    };
    auto stageV = [&](int kv0) {
      #pragma unroll
      for (int it = 0; it < 2; ++it) {
        const int r = it * 32 + sr8;       // d row
        const int g = sgr ^ (r & 7);
        gload_lds16(vtbase + (size_t)r * S_LEN + kv0 + g * 8,
                    vS + (it * 32 + wid * 8) * 64);
      }
    };

    float* abase = attn + (size_t)bh * S_LEN * S_LEN;
    f32x4 ctx[4];
    #pragma unroll
    for (int dt = 0; dt < 4; ++dt) ctx[dt] = (f32x4){0.f, 0.f, 0.f, 0.f};

    const int r2 = lane >> 4, c16 = lane & 15;   // store-phase lane mapping

    stageK(kS2a, 0);
    asm volatile("s_waitcnt vmcnt(0)" ::: "memory");
    __builtin_amdgcn_s_barrier();

    for (int t = 0; t < NT; ++t) {
      const int kv0 = t * 64;
      stageV(kv0);
      const bool pre = (t + 1 < NT);
      if (pre) stageK((t & 1) ? kS2a : kS2b, kv0 + 64);

      const u16* ks = (t & 1) ? kS2b : kS2a;
      const bool maskc = (kv0 + 63 > qw);
      #pragma unroll
      for (int g16 = 0; g16 < 4; ++g16) {
        const int r = g16 * 16 + l15;
        short8_t ka0 = *(const short8_t*)(ks + r * 64 + ((lg ^ (r & 7)) * 8));
        short8_t ka1 = *(const short8_t*)(ks + r * 64 + (((4 + lg) ^ (r & 7)) * 8));
        f32x4 sacc = (f32x4){0.f, 0.f, 0.f, 0.f};
        sacc = __builtin_amdgcn_mfma_f32_16x16x32_bf16(ka0, qf0, sacc, 0, 0, 0);
        sacc = __builtin_amdgcn_mfma_f32_16x16x32_bf16(ka1, qf1, sacc, 0, 0, 0);
        f32x4 pv;
        #pragma unroll
        for (int i = 0; i < 4; ++i) {
          float p = exp2med3(sacc[i]) * invl;
          if (maskc) {
            const int kvi = kv0 + g16 * 16 + lg * 4 + i;
            p = (kvi <= qrow) ? p : 0.f;
          }
          pv[i] = p;
        }
        // fp32 P tile, swizzled granule = logical granule XOR row
        *(f32x4*)&pF[l15][((g16 * 4 + lg) ^ l15) * 4] = pv;
      }

      // coalesced attn stores: instruction j covers rows j*4..j*4+3, 256 B/row contiguous
      #pragma unroll
      for (int j = 0; j < 4; ++j) {
        const int R = j * 4 + r2;
        f32x4 v = *(const f32x4*)&pF[R][(c16 ^ R) * 4];
        *(f32x4*)(abase + (size_t)(qw + R) * S_LEN + kv0 + c16 * 4) = v;
      }

      // V(t) ready: younger ops = (2 next-K if pre) + 4 stores stay in flight
      if (pre) asm volatile("s_waitcnt vmcnt(6)" ::: "memory");
      else     asm volatile("s_waitcnt vmcnt(4)" ::: "memory");
      __builtin_amdgcn_s_barrier();

      // PV operands from pF
      f32x4 alo = *(const f32x4*)&pF[l15][((2 * lg) ^ l15) * 4];
      f32x4 ahi = *(const f32x4*)&pF[l15][((2 * lg + 1) ^ l15) * 4];
      f32x4 blo = *(const f32x4*)&pF[l15][((8 + 2 * lg) ^ l15) * 4];
      f32x4 bhi = *(const f32x4*)&pF[l15][((9 + 2 * lg) ^ l15) * 4];
      short8_t pa0 = pack8(alo, ahi);
      short8_t pa1 = pack8(blo, bhi);
      #pragma unroll
      for (int dt = 0; dt < 4; ++dt) {
        const int r = dt * 16 + l15;
        short8_t bv0 = *(const short8_t*)(vS + r * 64 + ((lg ^ (r & 7)) * 8));
        short8_t bv1 = *(const short8_t*)(vS + r * 64 + (((4 + lg) ^ (r & 7)) * 8));
        ctx[dt] = __builtin_amdgcn_mfma_f32_16x16x32_bf16(bv0, pa0, ctx[dt], 0, 0, 0);
        ctx[dt] = __builtin_amdgcn_mfma_f32_16x16x32_bf16(bv1, pa1, ctx[dt], 0, 0, 0);
      }

      if (pre) {
        asm volatile("s_waitcnt vmcnt(4)" ::: "memory");
        __builtin_amdgcn_s_barrier();
      }
    }

    // ctx -> bf16 ctxb (coalesced u16x4): lane q = qrow, d = dt*16 + lg*4 + i
    #pragma unroll
    for (int dt = 0; dt < 4; ++dt) {
      u16x4 o;
      #pragma unroll
      for (int i = 0; i < 4; ++i) o[i] = f2bf(ctx[dt][i]);
      *(u16x4*)(ctxb + (size_t)(b * S_LEN + qrow) * HID_DIM + h * DHEAD + dt * 16 + lg * 4) = o;
    }

    // zero-fill attn cols [q0+64, S)
    const int zc0 = q0 + 64;
    if (zc0 < S_LEN) {
      const f32x4 z = (f32x4){0.f, 0.f, 0.f, 0.f};
      for (int r = wid; r < 64; r += 4) {
        float* rowp = abase + (size_t)(q0 + r) * S_LEN;
        for (int c = zc0 + lane * 4; c < S_LEN; c += 256)
          *(f32x4*)(rowp + c) = z;
      }
    }
  }
}

// ---------------------------------------------------------------- launch
extern "C" void kernel_launch(void* const* d_in, const int* in_sizes, int n_in,
                              void* d_out, int out_size, void* d_ws, size_t ws_size,
                              hipStream_t stream) {
  (void)in_sizes; (void)n_in; (void)out_size; (void)ws_size;
  const float* X    = (const float*)d_in[0];
  const float* cosb = (const float*)d_in[1];
  const float* sinb = (const float*)d_in[2];
  const float* Wq = (const float*)d_in[4];
  const float* bq = (const float*)d_in[5];
  const float* Wk = (const float*)d_in[6];
  const float* bk = (const float*)d_in[7];
  const float* Wv = (const float*)d_in[8];
  const float* bv = (const float*)d_in[9];
  const float* Wo = (const float*)d_in[10];
  const float* bo = (const float*)d_in[11];

  float* outp  = (float*)d_out;
  float* attnp = outp + (size_t)BATCH * S_LEN * HID_DIM;

  const int M = BATCH * S_LEN;           // 4096
  u16* ws    = (u16*)d_ws;
  u16* Xb    = ws;
  u16* Wqb   = Xb  + (size_t)M * HID_DIM;
  u16* Wkb   = Wqb + (size_t)HID_DIM * HID_DIM;
  u16* Wvb   = Wkb + (size_t)NKV * DHEAD * HID_DIM;
  u16* Wob   = Wvb + (size_t)NKV * DHEAD * HID_DIM;
  u16* qbuf  = Wob + (size_t)HID_DIM * HID_DIM;
  u16* kbuf  = qbuf + (size_t)M * HID_DIM;
  u16* vtbuf = kbuf + (size_t)M * NKV * DHEAD;     // [b][kvh][d][s] = (512, 2048)
  u16* ctxb  = vtbuf + (size_t)M * NKV * DHEAD;

  cast_all<<<dim3(1024, 5), 256, 0, stream>>>(X, Xb, Wq, Wqb, Wk, Wkb, Wv, Wvb, Wo, Wob);

  gemm_qkv<<<dim3(M / 64, 12), 256, 0, stream>>>(Xb, Wqb, Wkb, Wvb, bq, bk, bv,
                                                 cosb, sinb, qbuf, kbuf, vtbuf);

  attn_fused<<<dim3(BATCH * NHEAD, S_LEN / 64), 256, 0, stream>>>(qbuf, kbuf, vtbuf, attnp, ctxb);

  gemm_out<<<dim3(M / 64, HID_DIM / 128), 256, 0, stream>>>(ctxb, Wob, bo, outp);
}

// Round 17
// 205.737 us; speedup vs baseline: 1.0173x; 1.0173x over previous
//
#include <hip/hip_runtime.h>
#include <cstdint>
#include <cstddef>

// Problem constants (B=2, S=2048, HID=1024, H=16, KVH=4, D=64)
#define S_LEN   2048
#define BATCH   2
#define HID_DIM 1024
#define NHEAD   16
#define NKV     4
#define DHEAD   64
#define SCALE_F 0.125f
#define L2E     1.44269504f
#define QSCALE  (SCALE_F * L2E)          // folded into q at projection time
#define CAPL2   (50.0f * L2E)            // clamp bound in log2 space

typedef unsigned short u16;
typedef __attribute__((ext_vector_type(8))) short  short8_t;  // 8 bf16
typedef __attribute__((ext_vector_type(4))) float  f32x4;
typedef __attribute__((ext_vector_type(4))) u16    u16x4;

static __device__ __forceinline__ u16 f2bf(float f) {
  uint32_t x = __builtin_bit_cast(uint32_t, f);
  x += 0x7fffu + ((x >> 16) & 1u);
  return (u16)(x >> 16);
}
static __device__ __forceinline__ float bf2f(u16 u) {
  return __builtin_bit_cast(float, (uint32_t)u << 16);
}

static __device__ __forceinline__ void gload_lds16(const void* g, void* l) {
  __builtin_amdgcn_global_load_lds((const __attribute__((address_space(1))) void*)g,
                                   (__attribute__((address_space(3))) void*)l, 16, 0, 0);
}

// e = 2^(clamp(x, -CAPL2, CAPL2)); the -CAPL2 shift cancels in softmax normalization
static __device__ __forceinline__ float exp2med3(float x) {
  return __builtin_amdgcn_exp2f(__builtin_amdgcn_fmed3f(x, -CAPL2, CAPL2));
}

// ---------------------------------------------------------------- fused fp32->bf16 casts
__global__ void cast_all(const float* __restrict__ X,  u16* __restrict__ xb,
                         const float* __restrict__ Wq, u16* __restrict__ wqb,
                         const float* __restrict__ Wk, u16* __restrict__ wkb,
                         const float* __restrict__ Wv, u16* __restrict__ wvb,
                         const float* __restrict__ Wo, u16* __restrict__ wob) {
  const float* src; u16* dst; int n4;
  switch (blockIdx.y) {
    case 0:  src = X;  dst = xb;  n4 = (BATCH * S_LEN * HID_DIM) / 4; break;
    case 1:  src = Wq; dst = wqb; n4 = (HID_DIM * HID_DIM) / 4;       break;
    case 2:  src = Wk; dst = wkb; n4 = (NKV * DHEAD * HID_DIM) / 4;   break;
    case 3:  src = Wv; dst = wvb; n4 = (NKV * DHEAD * HID_DIM) / 4;   break;
    default: src = Wo; dst = wob; n4 = (HID_DIM * HID_DIM) / 4;       break;
  }
  for (int i = blockIdx.x * 256 + threadIdx.x; i < n4; i += gridDim.x * 256) {
    f32x4 v = ((const f32x4*)src)[i];
    u16x4 o;
    o[0] = f2bf(v[0]); o[1] = f2bf(v[1]); o[2] = f2bf(v[2]); o[3] = f2bf(v[3]);
    ((u16x4*)dst)[i] = o;
  }
}

// ---------------------------------------------------------------- fused QKV GEMM + RoPE + V^T
// BM=64, BN=128, BK=64, 4 waves (2x2; wave tile 32x64). Grid (M/64, 12) = 768 blocks.
__global__ __launch_bounds__(256, 4) void gemm_qkv(const u16* __restrict__ Xb,
                                                   const u16* __restrict__ Wqb,
                                                   const u16* __restrict__ Wkb,
                                                   const u16* __restrict__ Wvb,
                                                   const float* __restrict__ bq,
                                                   const float* __restrict__ bk,
                                                   const float* __restrict__ bv,
                                                   const float* __restrict__ cosb,
                                                   const float* __restrict__ sinb,
                                                   u16* __restrict__ qout,
                                                   u16* __restrict__ kout,
                                                   u16* __restrict__ vtout) {
  __shared__ u16 As[64 * 64];
  __shared__ u16 Bs[128 * 64];
  const int tid = threadIdx.x, lane = tid & 63, wid = tid >> 6;
  const int l15 = lane & 15, lg = lane >> 4;
  const int m0 = blockIdx.x * 64, n0 = blockIdx.y * 128;
  const int wm = wid & 1, wn = wid >> 1;
  const int K = HID_DIM;

  const u16* Wp; const float* biasp; int nl, mode;
  if (n0 < 1024)      { Wp = Wqb; biasp = bq; nl = n0;        mode = 0; }
  else if (n0 < 1280) { Wp = Wkb; biasp = bk; nl = n0 - 1024; mode = 1; }
  else                { Wp = Wvb; biasp = bv; nl = n0 - 1280; mode = 2; }

  f32x4 acc[4][2];   // [fn][fm]
  #pragma unroll
  for (int a = 0; a < 4; ++a)
    #pragma unroll
    for (int b2 = 0; b2 < 2; ++b2) acc[a][b2] = (f32x4){0.f, 0.f, 0.f, 0.f};

  const int srow = (lane >> 3), sg = (lane & 7);

  for (int kk = 0; kk < K; kk += 64) {
    __syncthreads();
    #pragma unroll
    for (int i = 0; i < 6; ++i) {              // 24 chunks of 8 rows: 8 A + 16 B
      const int c = wid * 6 + i;
      if (c < 8) {
        const int r = c * 8 + srow;
        const int g = sg ^ (r & 7);
        gload_lds16(Xb + (size_t)(m0 + r) * K + kk + g * 8, As + c * 512);
      } else {
        const int cb = c - 8;
        const int r = cb * 8 + srow;
        const int g = sg ^ (r & 7);
        gload_lds16(Wp + (size_t)(nl + r) * K + kk + g * 8, Bs + cb * 512);
      }
    }
    __syncthreads();
    #pragma unroll
    for (int ks = 0; ks < 2; ++ks) {
      short8_t xa[2], wb[4];
      #pragma unroll
      for (int f = 0; f < 2; ++f) {
        const int rm = wm * 32 + f * 16 + l15;
        xa[f] = *(const short8_t*)(As + rm * 64 + (((ks * 4 + lg) ^ (rm & 7)) * 8));
      }
      #pragma unroll
      for (int f = 0; f < 4; ++f) {
        const int rn = wn * 64 + f * 16 + l15;
        wb[f] = *(const short8_t*)(Bs + rn * 64 + (((ks * 4 + lg) ^ (rn & 7)) * 8));
      }
      if (mode != 2) {
        #pragma unroll
        for (int fn = 0; fn < 4; ++fn)
          #pragma unroll
          for (int fm = 0; fm < 2; ++fm)
            acc[fn][fm] = __builtin_amdgcn_mfma_f32_16x16x32_bf16(wb[fn], xa[fm], acc[fn][fm], 0, 0, 0);
      } else {
        #pragma unroll
        for (int fn = 0; fn < 4; ++fn)
          #pragma unroll
          for (int fm = 0; fm < 2; ++fm)
            acc[fn][fm] = __builtin_amdgcn_mfma_f32_16x16x32_bf16(xa[fm], wb[fn], acc[fn][fm], 0, 0, 0);
      }
    }
  }

  const int m_base = m0 + wm * 32;
  const int nlb = nl + wn * 64;

  if (mode < 2) {
    const int Nout = (mode == 0) ? HID_DIM : (NKV * DHEAD);
    const float qs = (mode == 0) ? QSCALE : 1.0f;
    u16* outb = (mode == 0) ? qout : kout;
    #pragma unroll
    for (int fm = 0; fm < 2; ++fm) {
      const int row = m_base + fm * 16 + l15;
      #pragma unroll
      for (int fn = 0; fn < 2; ++fn) {
        const int dh = fn * 16 + lg * 4;          // in [0,32)
        const f32x4 c4 = *(const f32x4*)(cosb + (size_t)row * 64 + dh);
        const f32x4 s4 = *(const f32x4*)(sinb + (size_t)row * 64 + dh);
        f32x4 x1 = acc[fn][fm]     + *(const f32x4*)(biasp + nlb + fn * 16 + lg * 4);
        f32x4 x2 = acc[fn + 2][fm] + *(const f32x4*)(biasp + nlb + (fn + 2) * 16 + lg * 4);
        f32x4 o1 = (x1 * c4 - x2 * s4) * qs;
        f32x4 o2 = (x2 * c4 + x1 * s4) * qs;
        u16x4 u1, u2;
        #pragma unroll
        for (int i = 0; i < 4; ++i) { u1[i] = f2bf(o1[i]); u2[i] = f2bf(o2[i]); }
        *(u16x4*)(outb + (size_t)row * Nout + nlb + fn * 16 + lg * 4)       = u1;
        *(u16x4*)(outb + (size_t)row * Nout + nlb + (fn + 2) * 16 + lg * 4) = u2;
      }
    }
  } else {
    // acc[fn][fm] holds D[d][s]: d = nlb+fn*16+l15, s = m_base+fm*16+lg*4+i
    #pragma unroll
    for (int fn = 0; fn < 4; ++fn) {
      const int d = nlb + fn * 16 + l15;
      const float bvs = biasp[d];
      #pragma unroll
      for (int fm = 0; fm < 2; ++fm) {
        const int s0 = m_base + fm * 16 + lg * 4;
        const int b_ = s0 >> 11, s_ = s0 & (S_LEN - 1);
        u16x4 o;
        #pragma unroll
        for (int i = 0; i < 4; ++i) o[i] = f2bf(acc[fn][fm][i] + bvs);
        *(u16x4*)(vtout + (size_t)(b_ * 256 + d) * S_LEN + s_) = o;
      }
    }
  }
}

// ---------------------------------------------------------------- out-proj GEMM (fp32 out)
// BM=64, BN=128: grid (64, 8) = 512 blocks.
__global__ __launch_bounds__(256, 4) void gemm_out(const u16* __restrict__ A,
                                                   const u16* __restrict__ W,
                                                   const float* __restrict__ bias,
                                                   float* __restrict__ outp) {
  __shared__ u16 As[64 * 64];
  __shared__ u16 Bs[128 * 64];
  const int tid = threadIdx.x, lane = tid & 63, wid = tid >> 6;
  const int l15 = lane & 15, lg = lane >> 4;
  const int m0 = blockIdx.x * 64, n0 = blockIdx.y * 128;
  const int wm = wid & 1, wn = wid >> 1;
  const int K = HID_DIM, N = HID_DIM;

  f32x4 acc[4][2];
  #pragma unroll
  for (int a = 0; a < 4; ++a)
    #pragma unroll
    for (int b2 = 0; b2 < 2; ++b2) acc[a][b2] = (f32x4){0.f, 0.f, 0.f, 0.f};

  const int srow = (lane >> 3), sg = (lane & 7);

  for (int kk = 0; kk < K; kk += 64) {
    __syncthreads();
    #pragma unroll
    for (int i = 0; i < 6; ++i) {
      const int c = wid * 6 + i;
      if (c < 8) {
        const int r = c * 8 + srow;
        const int g = sg ^ (r & 7);
        gload_lds16(A + (size_t)(m0 + r) * K + kk + g * 8, As + c * 512);
      } else {
        const int cb = c - 8;
        const int r = cb * 8 + srow;
        const int g = sg ^ (r & 7);
        gload_lds16(W + (size_t)(n0 + r) * K + kk + g * 8, Bs + cb * 512);
      }
    }
    __syncthreads();
    #pragma unroll
    for (int ks = 0; ks < 2; ++ks) {
      short8_t xa[2], wb[4];
      #pragma unroll
      for (int f = 0; f < 2; ++f) {
        const int rm = wm * 32 + f * 16 + l15;
        xa[f] = *(const short8_t*)(As + rm * 64 + (((ks * 4 + lg) ^ (rm & 7)) * 8));
      }
      #pragma unroll
      for (int f = 0; f < 4; ++f) {
        const int rn = wn * 64 + f * 16 + l15;
        wb[f] = *(const short8_t*)(Bs + rn * 64 + (((ks * 4 + lg) ^ (rn & 7)) * 8));
      }
      #pragma unroll
      for (int fn = 0; fn < 4; ++fn)
        #pragma unroll
        for (int fm = 0; fm < 2; ++fm)
          acc[fn][fm] = __builtin_amdgcn_mfma_f32_16x16x32_bf16(wb[fn], xa[fm], acc[fn][fm], 0, 0, 0);
    }
  }

  const int m_base = m0 + wm * 32, n_base = n0 + wn * 64;
  #pragma unroll
  for (int fn = 0; fn < 4; ++fn) {
    const int col = n_base + fn * 16 + lg * 4;
    const f32x4 bvv = *(const f32x4*)(bias + col);
    #pragma unroll
    for (int fm = 0; fm < 2; ++fm) {
      const int row = m_base + fm * 16 + l15;
      *(f32x4*)(outp + (size_t)row * N + col) = acc[fn][fm] + bvv;
    }
  }
}

// ---------------------------------------------------------------- fused causal attention
// grid (B*H, S/64), 256 thr (4 waves x 16 q-rows = KVBLK=64). LDS EXACTLY 32 KB
// (kS dbuf 16 + vS 8 + pB 8) -> 5 blocks/CU (launch_bounds(256,5)): +25% resident
// store streams smooths the burst store pattern. P tile is bf16 (pB, row-XOR 8B
// granules, all accesses at LDS wave floor); attn stores widen bf16->fp32 on the fly
// (adds <=0.004 abs, threshold 0.081). Schedule identical to R15 (2-barrier prefetch).
__global__ __launch_bounds__(256, 5) void attn_fused(const u16* __restrict__ qb,
                                                     const u16* __restrict__ kb,
                                                     const u16* __restrict__ vtb,
                                                     float* __restrict__ attn,
                                                     u16* __restrict__ ctxb) {
  __shared__ u16 kS[2][64 * 64];   // 16 KB
  __shared__ u16 vS[64 * 64];      //  8 KB
  __shared__ u16 pB[4][16][64];    //  8 KB  per-wave bf16 P, granule g stored at g^row

  const int tid = threadIdx.x, lane = tid & 63, wid = tid >> 6;
  const int l15 = lane & 15, lg = lane >> 4;
  const int bh = blockIdx.x, b = bh >> 4, h = bh & 15, kvh = h >> 2;
  const int qt = (int)(gridDim.y - 1 - blockIdx.y);   // longest-first
  const int q0 = qt * 64;
  const int NT = qt + 1;
  const int qw = q0 + wid * 16;
  const int qrow = qw + l15;

  const u16* qp = qb + (size_t)(b * S_LEN + qrow) * HID_DIM + h * DHEAD + lg * 8;
  const short8_t qf0 = *(const short8_t*)qp;
  const short8_t qf1 = *(const short8_t*)(qp + 32);

  const u16* kbase  = kb  + (size_t)(b * S_LEN) * (NKV * DHEAD) + kvh * DHEAD;
  const u16* vtbase = vtb + (size_t)(b * NKV + kvh) * DHEAD * S_LEN;

  const int sr8 = wid * 8 + (lane >> 3);   // staging row within 32-row half
  const int sgr = lane & 7;

  auto stageK = [&](int bi, int kv0) {
    #pragma unroll
    for (int it = 0; it < 2; ++it) {
      const int r = it * 32 + sr8;
      const int g = sgr ^ (r & 7);
      gload_lds16(kbase + (size_t)(kv0 + r) * (NKV * DHEAD) + g * 8,
                  &kS[bi][(it * 32 + wid * 8) * 64]);
    }
  };
  auto stageV = [&](int kv0) {
    #pragma unroll
    for (int it = 0; it < 2; ++it) {
      const int r = it * 32 + sr8;         // d row
      const int g = sgr ^ (r & 7);
      gload_lds16(vtbase + (size_t)r * S_LEN + kv0 + g * 8,
                  &vS[(it * 32 + wid * 8) * 64]);
    }
  };

  // ---------------- pass 1: lsum = sum 2^med3(s')   (constant shift cancels; no stores)
  f32x4 lacc = (f32x4){0.f, 0.f, 0.f, 0.f};
  stageK(0, 0);
  for (int t = 0; t < NT; ++t) {
    const int kv0 = t * 64;
    if (t + 1 < NT) {
      stageK((t + 1) & 1, kv0 + 64);
      asm volatile("s_waitcnt vmcnt(2)" ::: "memory");
    } else {
      asm volatile("s_waitcnt vmcnt(0)" ::: "memory");
    }
    __builtin_amdgcn_s_barrier();
    const u16* ks = kS[t & 1];
    const bool maskc = (kv0 + 63 > qw);
    #pragma unroll
    for (int g16 = 0; g16 < 4; ++g16) {
      const int r = g16 * 16 + l15;
      short8_t ka0 = *(const short8_t*)(ks + r * 64 + ((lg ^ (r & 7)) * 8));
      short8_t ka1 = *(const short8_t*)(ks + r * 64 + (((4 + lg) ^ (r & 7)) * 8));
      f32x4 sacc = (f32x4){0.f, 0.f, 0.f, 0.f};
      sacc = __builtin_amdgcn_mfma_f32_16x16x32_bf16(ka0, qf0, sacc, 0, 0, 0);
      sacc = __builtin_amdgcn_mfma_f32_16x16x32_bf16(ka1, qf1, sacc, 0, 0, 0);
      #pragma unroll
      for (int i = 0; i < 4; ++i) {
        float e = exp2med3(sacc[i]);
        if (maskc) {
          const int kvi = kv0 + g16 * 16 + lg * 4 + i;
          e = (kvi <= qrow) ? e : 0.f;
        }
        lacc[i] += e;
      }
    }
    __builtin_amdgcn_s_barrier();
  }
  float lsum = (lacc[0] + lacc[1]) + (lacc[2] + lacc[3]);
  lsum += __shfl_xor(lsum, 16);
  lsum += __shfl_xor(lsum, 32);
  const float invl = 1.f / lsum;

  // ---------------- pass 2: QK -> pB (bf16) -> 256B-contiguous fp32 stores + PV
  float* abase = attn + (size_t)bh * S_LEN * S_LEN;
  f32x4 ctx[4];
  #pragma unroll
  for (int dt = 0; dt < 4; ++dt) ctx[dt] = (f32x4){0.f, 0.f, 0.f, 0.f};

  const int r2 = lane >> 4, c16 = lane & 15;   // store-phase lane mapping

  stageK(0, 0);
  asm volatile("s_waitcnt vmcnt(0)" ::: "memory");
  __builtin_amdgcn_s_barrier();

  for (int t = 0; t < NT; ++t) {
    const int kv0 = t * 64;
    stageV(kv0);
    const bool pre = (t + 1 < NT);
    if (pre) stageK((t + 1) & 1, kv0 + 64);

    const u16* ks = kS[t & 1];
    const bool maskc = (kv0 + 63 > qw);
    #pragma unroll
    for (int g16 = 0; g16 < 4; ++g16) {
      const int r = g16 * 16 + l15;
      short8_t ka0 = *(const short8_t*)(ks + r * 64 + ((lg ^ (r & 7)) * 8));
      short8_t ka1 = *(const short8_t*)(ks + r * 64 + (((4 + lg) ^ (r & 7)) * 8));
      f32x4 sacc = (f32x4){0.f, 0.f, 0.f, 0.f};
      sacc = __builtin_amdgcn_mfma_f32_16x16x32_bf16(ka0, qf0, sacc, 0, 0, 0);
      sacc = __builtin_amdgcn_mfma_f32_16x16x32_bf16(ka1, qf1, sacc, 0, 0, 0);
      u16x4 pb;
      #pragma unroll
      for (int i = 0; i < 4; ++i) {
        float p = exp2med3(sacc[i]) * invl;
        if (maskc) {
          const int kvi = kv0 + g16 * 16 + lg * 4 + i;
          p = (kvi <= qrow) ? p : 0.f;
        }
        pb[i] = f2bf(p);
      }
      // bf16 P tile, 8B granule g = g16*4+lg stored at g ^ row
      *(u16x4*)&pB[wid][l15][((g16 * 4 + lg) ^ l15) * 4] = pb;
    }

    // coalesced attn stores: instruction j covers rows j*4..j*4+3, 256 B/row contiguous
    #pragma unroll
    for (int j = 0; j < 4; ++j) {
      const int R = j * 4 + r2;
      u16x4 pv4 = *(const u16x4*)&pB[wid][R][(c16 ^ R) * 4];
      f32x4 v;
      #pragma unroll
      for (int i = 0; i < 4; ++i) v[i] = bf2f(pv4[i]);
      *(f32x4*)(abase + (size_t)(qw + R) * S_LEN + kv0 + c16 * 4) = v;
    }

    // V(t) ready: younger ops = (2 next-K if pre) + 4 stores stay in flight
    if (pre) asm volatile("s_waitcnt vmcnt(6)" ::: "memory");
    else     asm volatile("s_waitcnt vmcnt(4)" ::: "memory");
    __builtin_amdgcn_s_barrier();

    // PV operands directly from pB (no repack): granules 2lg,2lg+1 and 8+2lg,9+2lg
    u16x4 a0 = *(const u16x4*)&pB[wid][l15][((2 * lg) ^ l15) * 4];
    u16x4 a1 = *(const u16x4*)&pB[wid][l15][((2 * lg + 1) ^ l15) * 4];
    u16x4 b0 = *(const u16x4*)&pB[wid][l15][((8 + 2 * lg) ^ l15) * 4];
    u16x4 b1 = *(const u16x4*)&pB[wid][l15][((9 + 2 * lg) ^ l15) * 4];
    short8_t pa0, pa1;
    #pragma unroll
    for (int i = 0; i < 4; ++i) {
      pa0[i] = (short)a0[i]; pa0[i + 4] = (short)a1[i];
      pa1[i] = (short)b0[i]; pa1[i + 4] = (short)b1[i];
    }
    #pragma unroll
    for (int dt = 0; dt < 4; ++dt) {
      const int r = dt * 16 + l15;
      short8_t bv0 = *(const short8_t*)(vS + r * 64 + ((lg ^ (r & 7)) * 8));
      short8_t bv1 = *(const short8_t*)(vS + r * 64 + (((4 + lg) ^ (r & 7)) * 8));
      ctx[dt] = __builtin_amdgcn_mfma_f32_16x16x32_bf16(bv0, pa0, ctx[dt], 0, 0, 0);
      ctx[dt] = __builtin_amdgcn_mfma_f32_16x16x32_bf16(bv1, pa1, ctx[dt], 0, 0, 0);
    }

    if (pre) {
      asm volatile("s_waitcnt vmcnt(4)" ::: "memory");
      __builtin_amdgcn_s_barrier();
    }
  }

  // ctx -> bf16 ctxb (coalesced u16x4): lane q = qrow, d = dt*16 + lg*4 + i
  #pragma unroll
  for (int dt = 0; dt < 4; ++dt) {
    u16x4 o;
    #pragma unroll
    for (int i = 0; i < 4; ++i) o[i] = f2bf(ctx[dt][i]);
    *(u16x4*)(ctxb + (size_t)(b * S_LEN + qrow) * HID_DIM + h * DHEAD + dt * 16 + lg * 4) = o;
  }

  // zero-fill attn cols [q0+64, S)
  const int zc0 = q0 + 64;
  if (zc0 < S_LEN) {
    const f32x4 z = (f32x4){0.f, 0.f, 0.f, 0.f};
    for (int r = wid; r < 64; r += 4) {
      float* rowp = abase + (size_t)(q0 + r) * S_LEN;
      for (int c = zc0 + lane * 4; c < S_LEN; c += 256)
        *(f32x4*)(rowp + c) = z;
    }
  }
}

// ---------------------------------------------------------------- launch
extern "C" void kernel_launch(void* const* d_in, const int* in_sizes, int n_in,
                              void* d_out, int out_size, void* d_ws, size_t ws_size,
                              hipStream_t stream) {
  (void)in_sizes; (void)n_in; (void)out_size; (void)ws_size;
  const float* X    = (const float*)d_in[0];
  const float* cosb = (const float*)d_in[1];
  const float* sinb = (const float*)d_in[2];
  const float* Wq = (const float*)d_in[4];
  const float* bq = (const float*)d_in[5];
  const float* Wk = (const float*)d_in[6];
  const float* bk = (const float*)d_in[7];
  const float* Wv = (const float*)d_in[8];
  const float* bv = (const float*)d_in[9];
  const float* Wo = (const float*)d_in[10];
  const float* bo = (const float*)d_in[11];

  float* outp  = (float*)d_out;
  float* attnp = outp + (size_t)BATCH * S_LEN * HID_DIM;

  const int M = BATCH * S_LEN;           // 4096
  u16* ws    = (u16*)d_ws;
  u16* Xb    = ws;
  u16* Wqb   = Xb  + (size_t)M * HID_DIM;
  u16* Wkb   = Wqb + (size_t)HID_DIM * HID_DIM;
  u16* Wvb   = Wkb + (size_t)NKV * DHEAD * HID_DIM;
  u16* Wob   = Wvb + (size_t)NKV * DHEAD * HID_DIM;
  u16* qbuf  = Wob + (size_t)HID_DIM * HID_DIM;
  u16* kbuf  = qbuf + (size_t)M * HID_DIM;
  u16* vtbuf = kbuf + (size_t)M * NKV * DHEAD;     // [b][kvh][d][s] = (512, 2048)
  u16* ctxb  = vtbuf + (size_t)M * NKV * DHEAD;

  cast_all<<<dim3(1024, 5), 256, 0, stream>>>(X, Xb, Wq, Wqb, Wk, Wkb, Wv, Wvb, Wo, Wob);

  gemm_qkv<<<dim3(M / 64, 12), 256, 0, stream>>>(Xb, Wqb, Wkb, Wvb, bq, bk, bv,
                                                 cosb, sinb, qbuf, kbuf, vtbuf);

  attn_fused<<<dim3(BATCH * NHEAD, S_LEN / 64), 256, 0, stream>>>(qbuf, kbuf, vtbuf, attnp, ctxb);

  gemm_out<<<dim3(M / 64, HID_DIM / 128), 256, 0, stream>>>(ctxb, Wob, bo, outp);
}

// Round 18
// 199.363 us; speedup vs baseline: 1.0499x; 1.0320x over previous
//
#include <hip/hip_runtime.h>
#include <cstdint>
#include <cstddef>

// Problem constants (B=2, S=2048, HID=1024, H=16, KVH=4, D=64)
#define S_LEN   2048
#define BATCH   2
#define HID_DIM 1024
#define NHEAD   16
#define NKV     4
#define DHEAD   64
#define SCALE_F 0.125f
#define L2E     1.44269504f
#define QSCALE  (SCALE_F * L2E)          // folded into q at projection time
#define CAPL2   (50.0f * L2E)            // clamp bound in log2 space

typedef unsigned short u16;
typedef __attribute__((ext_vector_type(8))) short  short8_t;  // 8 bf16
typedef __attribute__((ext_vector_type(4))) float  f32x4;
typedef __attribute__((ext_vector_type(4))) u16    u16x4;

static __device__ __forceinline__ u16 f2bf(float f) {
  uint32_t x = __builtin_bit_cast(uint32_t, f);
  x += 0x7fffu + ((x >> 16) & 1u);
  return (u16)(x >> 16);
}

static __device__ __forceinline__ void gload_lds16(const void* g, void* l) {
  __builtin_amdgcn_global_load_lds((const __attribute__((address_space(1))) void*)g,
                                   (__attribute__((address_space(3))) void*)l, 16, 0, 0);
}

// e = 2^(clamp(x, -CAPL2, CAPL2)); the -CAPL2 shift cancels in softmax normalization
static __device__ __forceinline__ float exp2med3(float x) {
  return __builtin_amdgcn_exp2f(__builtin_amdgcn_fmed3f(x, -CAPL2, CAPL2));
}

static __device__ __forceinline__ short8_t pack8(f32x4 a, f32x4 b) {
  short8_t r;
  r[0] = (short)f2bf(a[0]); r[1] = (short)f2bf(a[1]);
  r[2] = (short)f2bf(a[2]); r[3] = (short)f2bf(a[3]);
  r[4] = (short)f2bf(b[0]); r[5] = (short)f2bf(b[1]);
  r[6] = (short)f2bf(b[2]); r[7] = (short)f2bf(b[3]);
  return r;
}

// ---------------------------------------------------------------- fused fp32->bf16 casts
__global__ void cast_all(const float* __restrict__ X,  u16* __restrict__ xb,
                         const float* __restrict__ Wq, u16* __restrict__ wqb,
                         const float* __restrict__ Wk, u16* __restrict__ wkb,
                         const float* __restrict__ Wv, u16* __restrict__ wvb,
                         const float* __restrict__ Wo, u16* __restrict__ wob) {
  const float* src; u16* dst; int n4;
  switch (blockIdx.y) {
    case 0:  src = X;  dst = xb;  n4 = (BATCH * S_LEN * HID_DIM) / 4; break;
    case 1:  src = Wq; dst = wqb; n4 = (HID_DIM * HID_DIM) / 4;       break;
    case 2:  src = Wk; dst = wkb; n4 = (NKV * DHEAD * HID_DIM) / 4;   break;
    case 3:  src = Wv; dst = wvb; n4 = (NKV * DHEAD * HID_DIM) / 4;   break;
    default: src = Wo; dst = wob; n4 = (HID_DIM * HID_DIM) / 4;       break;
  }
  for (int i = blockIdx.x * 256 + threadIdx.x; i < n4; i += gridDim.x * 256) {
    f32x4 v = ((const f32x4*)src)[i];
    u16x4 o;
    o[0] = f2bf(v[0]); o[1] = f2bf(v[1]); o[2] = f2bf(v[2]); o[3] = f2bf(v[3]);
    ((u16x4*)dst)[i] = o;
  }
}

// ---------------------------------------------------------------- fused QKV GEMM + RoPE + V^T
// BM=64, BN=128, BK=64, 4 waves (2x2; wave tile 32x64). Grid (M/64, 12) = 768 blocks.
__global__ __launch_bounds__(256, 4) void gemm_qkv(const u16* __restrict__ Xb,
                                                   const u16* __restrict__ Wqb,
                                                   const u16* __restrict__ Wkb,
                                                   const u16* __restrict__ Wvb,
                                                   const float* __restrict__ bq,
                                                   const float* __restrict__ bk,
                                                   const float* __restrict__ bv,
                                                   const float* __restrict__ cosb,
                                                   const float* __restrict__ sinb,
                                                   u16* __restrict__ qout,
                                                   u16* __restrict__ kout,
                                                   u16* __restrict__ vtout) {
  __shared__ u16 As[64 * 64];
  __shared__ u16 Bs[128 * 64];
  const int tid = threadIdx.x, lane = tid & 63, wid = tid >> 6;
  const int l15 = lane & 15, lg = lane >> 4;
  const int m0 = blockIdx.x * 64, n0 = blockIdx.y * 128;
  const int wm = wid & 1, wn = wid >> 1;
  const int K = HID_DIM;

  const u16* Wp; const float* biasp; int nl, mode;
  if (n0 < 1024)      { Wp = Wqb; biasp = bq; nl = n0;        mode = 0; }
  else if (n0 < 1280) { Wp = Wkb; biasp = bk; nl = n0 - 1024; mode = 1; }
  else                { Wp = Wvb; biasp = bv; nl = n0 - 1280; mode = 2; }

  f32x4 acc[4][2];   // [fn][fm]
  #pragma unroll
  for (int a = 0; a < 4; ++a)
    #pragma unroll
    for (int b2 = 0; b2 < 2; ++b2) acc[a][b2] = (f32x4){0.f, 0.f, 0.f, 0.f};

  const int srow = (lane >> 3), sg = (lane & 7);

  for (int kk = 0; kk < K; kk += 64) {
    __syncthreads();
    #pragma unroll
    for (int i = 0; i < 6; ++i) {              // 24 chunks of 8 rows: 8 A + 16 B
      const int c = wid * 6 + i;
      if (c < 8) {
        const int r = c * 8 + srow;
        const int g = sg ^ (r & 7);
        gload_lds16(Xb + (size_t)(m0 + r) * K + kk + g * 8, As + c * 512);
      } else {
        const int cb = c - 8;
        const int r = cb * 8 + srow;
        const int g = sg ^ (r & 7);
        gload_lds16(Wp + (size_t)(nl + r) * K + kk + g * 8, Bs + cb * 512);
      }
    }
    __syncthreads();
    #pragma unroll
    for (int ks = 0; ks < 2; ++ks) {
      short8_t xa[2], wb[4];
      #pragma unroll
      for (int f = 0; f < 2; ++f) {
        const int rm = wm * 32 + f * 16 + l15;
        xa[f] = *(const short8_t*)(As + rm * 64 + (((ks * 4 + lg) ^ (rm & 7)) * 8));
      }
      #pragma unroll
      for (int f = 0; f < 4; ++f) {
        const int rn = wn * 64 + f * 16 + l15;
        wb[f] = *(const short8_t*)(Bs + rn * 64 + (((ks * 4 + lg) ^ (rn & 7)) * 8));
      }
      if (mode != 2) {
        #pragma unroll
        for (int fn = 0; fn < 4; ++fn)
          #pragma unroll
          for (int fm = 0; fm < 2; ++fm)
            acc[fn][fm] = __builtin_amdgcn_mfma_f32_16x16x32_bf16(wb[fn], xa[fm], acc[fn][fm], 0, 0, 0);
      } else {
        #pragma unroll
        for (int fn = 0; fn < 4; ++fn)
          #pragma unroll
          for (int fm = 0; fm < 2; ++fm)
            acc[fn][fm] = __builtin_amdgcn_mfma_f32_16x16x32_bf16(xa[fm], wb[fn], acc[fn][fm], 0, 0, 0);
      }
    }
  }

  const int m_base = m0 + wm * 32;
  const int nlb = nl + wn * 64;

  if (mode < 2) {
    const int Nout = (mode == 0) ? HID_DIM : (NKV * DHEAD);
    const float qs = (mode == 0) ? QSCALE : 1.0f;
    u16* outb = (mode == 0) ? qout : kout;
    #pragma unroll
    for (int fm = 0; fm < 2; ++fm) {
      const int row = m_base + fm * 16 + l15;
      #pragma unroll
      for (int fn = 0; fn < 2; ++fn) {
        const int dh = fn * 16 + lg * 4;          // in [0,32)
        const f32x4 c4 = *(const f32x4*)(cosb + (size_t)row * 64 + dh);
        const f32x4 s4 = *(const f32x4*)(sinb + (size_t)row * 64 + dh);
        f32x4 x1 = acc[fn][fm]     + *(const f32x4*)(biasp + nlb + fn * 16 + lg * 4);
        f32x4 x2 = acc[fn + 2][fm] + *(const f32x4*)(biasp + nlb + (fn + 2) * 16 + lg * 4);
        f32x4 o1 = (x1 * c4 - x2 * s4) * qs;
        f32x4 o2 = (x2 * c4 + x1 * s4) * qs;
        u16x4 u1, u2;
        #pragma unroll
        for (int i = 0; i < 4; ++i) { u1[i] = f2bf(o1[i]); u2[i] = f2bf(o2[i]); }
        *(u16x4*)(outb + (size_t)row * Nout + nlb + fn * 16 + lg * 4)       = u1;
        *(u16x4*)(outb + (size_t)row * Nout + nlb + (fn + 2) * 16 + lg * 4) = u2;
      }
    }
  } else {
    // acc[fn][fm] holds D[d][s]: d = nlb+fn*16+l15, s = m_base+fm*16+lg*4+i
    #pragma unroll
    for (int fn = 0; fn < 4; ++fn) {
      const int d = nlb + fn * 16 + l15;
      const float bvs = biasp[d];
      #pragma unroll
      for (int fm = 0; fm < 2; ++fm) {
        const int s0 = m_base + fm * 16 + lg * 4;
        const int b_ = s0 >> 11, s_ = s0 & (S_LEN - 1);
        u16x4 o;
        #pragma unroll
        for (int i = 0; i < 4; ++i) o[i] = f2bf(acc[fn][fm][i] + bvs);
        *(u16x4*)(vtout + (size_t)(b_ * 256 + d) * S_LEN + s_) = o;
      }
    }
  }
}

// ---------------------------------------------------------------- out-proj GEMM (fp32 out)
// BM=64, BN=128: grid (64, 8) = 512 blocks.
__global__ __launch_bounds__(256, 4) void gemm_out(const u16* __restrict__ A,
                                                   const u16* __restrict__ W,
                                                   const float* __restrict__ bias,
                                                   float* __restrict__ outp) {
  __shared__ u16 As[64 * 64];
  __shared__ u16 Bs[128 * 64];
  const int tid = threadIdx.x, lane = tid & 63, wid = tid >> 6;
  const int l15 = lane & 15, lg = lane >> 4;
  const int m0 = blockIdx.x * 64, n0 = blockIdx.y * 128;
  const int wm = wid & 1, wn = wid >> 1;
  const int K = HID_DIM, N = HID_DIM;

  f32x4 acc[4][2];
  #pragma unroll
  for (int a = 0; a < 4; ++a)
    #pragma unroll
    for (int b2 = 0; b2 < 2; ++b2) acc[a][b2] = (f32x4){0.f, 0.f, 0.f, 0.f};

  const int srow = (lane >> 3), sg = (lane & 7);

  for (int kk = 0; kk < K; kk += 64) {
    __syncthreads();
    #pragma unroll
    for (int i = 0; i < 6; ++i) {
      const int c = wid * 6 + i;
      if (c < 8) {
        const int r = c * 8 + srow;
        const int g = sg ^ (r & 7);
        gload_lds16(A + (size_t)(m0 + r) * K + kk + g * 8, As + c * 512);
      } else {
        const int cb = c - 8;
        const int r = cb * 8 + srow;
        const int g = sg ^ (r & 7);
        gload_lds16(W + (size_t)(n0 + r) * K + kk + g * 8, Bs + cb * 512);
      }
    }
    __syncthreads();
    #pragma unroll
    for (int ks = 0; ks < 2; ++ks) {
      short8_t xa[2], wb[4];
      #pragma unroll
      for (int f = 0; f < 2; ++f) {
        const int rm = wm * 32 + f * 16 + l15;
        xa[f] = *(const short8_t*)(As + rm * 64 + (((ks * 4 + lg) ^ (rm & 7)) * 8));
      }
      #pragma unroll
      for (int f = 0; f < 4; ++f) {
        const int rn = wn * 64 + f * 16 + l15;
        wb[f] = *(const short8_t*)(Bs + rn * 64 + (((ks * 4 + lg) ^ (rn & 7)) * 8));
      }
      #pragma unroll
      for (int fn = 0; fn < 4; ++fn)
        #pragma unroll
        for (int fm = 0; fm < 2; ++fm)
          acc[fn][fm] = __builtin_amdgcn_mfma_f32_16x16x32_bf16(wb[fn], xa[fm], acc[fn][fm], 0, 0, 0);
    }
  }

  const int m_base = m0 + wm * 32, n_base = n0 + wn * 64;
  #pragma unroll
  for (int fn = 0; fn < 4; ++fn) {
    const int col = n_base + fn * 16 + lg * 4;
    const f32x4 bvv = *(const f32x4*)(bias + col);
    #pragma unroll
    for (int fm = 0; fm < 2; ++fm) {
      const int row = m_base + fm * 16 + l15;
      *(f32x4*)(outp + (size_t)row * N + col) = acc[fn][fm] + bvv;
    }
  }
}

// ---------------------------------------------------------------- fused causal attention
// grid (B*H, S/64), 256 thr (4 waves x 16 q-rows = KVBLK=64). LDS 40 KB (kS 16 + vS 8
// + pF 16) -> 4 blocks/CU. R15 structure + ONE change: the zero-fill (50% of attn
// bytes) moved from the END to BETWEEN pass 1 and pass 2. Blocks with small qt have
// tiny pass-1 and huge zero regions -> their zero-stores fill the HBM-write window
// that long-pass-1 blocks leave idle (chip-wide phase alignment flattened).
__global__ __launch_bounds__(256, 4) void attn_fused(const u16* __restrict__ qb,
                                                     const u16* __restrict__ kb,
                                                     const u16* __restrict__ vtb,
                                                     float* __restrict__ attn,
                                                     u16* __restrict__ ctxb) {
  __shared__ u16 kS[2][64 * 64];
  __shared__ u16 vS[64 * 64];
  __shared__ float pF[4][16][64];   // per-wave fp32 P tile, granule-XOR-swizzled

  const int tid = threadIdx.x, lane = tid & 63, wid = tid >> 6;
  const int l15 = lane & 15, lg = lane >> 4;
  const int bh = blockIdx.x, b = bh >> 4, h = bh & 15, kvh = h >> 2;
  const int qt = (int)(gridDim.y - 1 - blockIdx.y);   // longest-first
  const int q0 = qt * 64;
  const int NT = qt + 1;
  const int qw = q0 + wid * 16;
  const int qrow = qw + l15;

  const u16* qp = qb + (size_t)(b * S_LEN + qrow) * HID_DIM + h * DHEAD + lg * 8;
  const short8_t qf0 = *(const short8_t*)qp;
  const short8_t qf1 = *(const short8_t*)(qp + 32);

  const u16* kbase  = kb  + (size_t)(b * S_LEN) * (NKV * DHEAD) + kvh * DHEAD;
  const u16* vtbase = vtb + (size_t)(b * NKV + kvh) * DHEAD * S_LEN;

  const int sr8 = wid * 8 + (lane >> 3);   // staging row within 32-row half
  const int sgr = lane & 7;

  auto stageK = [&](int bi, int kv0) {
    #pragma unroll
    for (int it = 0; it < 2; ++it) {
      const int r = it * 32 + sr8;
      const int g = sgr ^ (r & 7);
      gload_lds16(kbase + (size_t)(kv0 + r) * (NKV * DHEAD) + g * 8,
                  &kS[bi][(it * 32 + wid * 8) * 64]);
    }
  };
  auto stageV = [&](int kv0) {
    #pragma unroll
    for (int it = 0; it < 2; ++it) {
      const int r = it * 32 + sr8;         // d row
      const int g = sgr ^ (r & 7);
      gload_lds16(vtbase + (size_t)r * S_LEN + kv0 + g * 8,
                  &vS[(it * 32 + wid * 8) * 64]);
    }
  };

  float* abase = attn + (size_t)bh * S_LEN * S_LEN;

  // ---------------- pass 1: lsum = sum 2^med3(s')   (constant shift cancels; no stores)
  f32x4 lacc = (f32x4){0.f, 0.f, 0.f, 0.f};
  stageK(0, 0);
  for (int t = 0; t < NT; ++t) {
    const int kv0 = t * 64;
    if (t + 1 < NT) {
      stageK((t + 1) & 1, kv0 + 64);
      asm volatile("s_waitcnt vmcnt(2)" ::: "memory");
    } else {
      asm volatile("s_waitcnt vmcnt(0)" ::: "memory");
    }
    __builtin_amdgcn_s_barrier();
    const u16* ks = kS[t & 1];
    const bool maskc = (kv0 + 63 > qw);
    #pragma unroll
    for (int g16 = 0; g16 < 4; ++g16) {
      const int r = g16 * 16 + l15;
      short8_t ka0 = *(const short8_t*)(ks + r * 64 + ((lg ^ (r & 7)) * 8));
      short8_t ka1 = *(const short8_t*)(ks + r * 64 + (((4 + lg) ^ (r & 7)) * 8));
      f32x4 sacc = (f32x4){0.f, 0.f, 0.f, 0.f};
      sacc = __builtin_amdgcn_mfma_f32_16x16x32_bf16(ka0, qf0, sacc, 0, 0, 0);
      sacc = __builtin_amdgcn_mfma_f32_16x16x32_bf16(ka1, qf1, sacc, 0, 0, 0);
      #pragma unroll
      for (int i = 0; i < 4; ++i) {
        float e = exp2med3(sacc[i]);
        if (maskc) {
          const int kvi = kv0 + g16 * 16 + lg * 4 + i;
          e = (kvi <= qrow) ? e : 0.f;
        }
        lacc[i] += e;
      }
    }
    __builtin_amdgcn_s_barrier();
  }
  float lsum = (lacc[0] + lacc[1]) + (lacc[2] + lacc[3]);
  lsum += __shfl_xor(lsum, 16);
  lsum += __shfl_xor(lsum, 32);
  const float invl = 1.f / lsum;

  // ---------------- zero-fill attn cols [q0+64, S)  (MOVED HERE: fills the HBM write
  // window while long-pass-1 blocks are still computing; small-qt blocks reach this
  // almost immediately and have the largest zero regions)
  const int zc0 = q0 + 64;
  if (zc0 < S_LEN) {
    const f32x4 z = (f32x4){0.f, 0.f, 0.f, 0.f};
    for (int r = wid; r < 64; r += 4) {
      float* rowp = abase + (size_t)(q0 + r) * S_LEN;
      for (int c = zc0 + lane * 4; c < S_LEN; c += 256)
        *(f32x4*)(rowp + c) = z;
    }
  }

  // ---------------- pass 2: QK -> pF (fp32) -> coalesced stores + PV
  f32x4 ctx[4];
  #pragma unroll
  for (int dt = 0; dt < 4; ++dt) ctx[dt] = (f32x4){0.f, 0.f, 0.f, 0.f};

  const int r2 = lane >> 4, c16 = lane & 15;   // store-phase lane mapping

  stageK(0, 0);
  asm volatile("s_waitcnt vmcnt(0)" ::: "memory");
  __builtin_amdgcn_s_barrier();

  for (int t = 0; t < NT; ++t) {
    const int kv0 = t * 64;
    stageV(kv0);
    const bool pre = (t + 1 < NT);
    if (pre) stageK((t + 1) & 1, kv0 + 64);

    const u16* ks = kS[t & 1];
    const bool maskc = (kv0 + 63 > qw);
    #pragma unroll
    for (int g16 = 0; g16 < 4; ++g16) {
      const int r = g16 * 16 + l15;
      short8_t ka0 = *(const short8_t*)(ks + r * 64 + ((lg ^ (r & 7)) * 8));
      short8_t ka1 = *(const short8_t*)(ks + r * 64 + (((4 + lg) ^ (r & 7)) * 8));
      f32x4 sacc = (f32x4){0.f, 0.f, 0.f, 0.f};
      sacc = __builtin_amdgcn_mfma_f32_16x16x32_bf16(ka0, qf0, sacc, 0, 0, 0);
      sacc = __builtin_amdgcn_mfma_f32_16x16x32_bf16(ka1, qf1, sacc, 0, 0, 0);
      f32x4 pv;
      #pragma unroll
      for (int i = 0; i < 4; ++i) {
        float p = exp2med3(sacc[i]) * invl;
        if (maskc) {
          const int kvi = kv0 + g16 * 16 + lg * 4 + i;
          p = (kvi <= qrow) ? p : 0.f;
        }
        pv[i] = p;
      }
      // fp32 P tile, swizzled granule = logical granule XOR row
      *(f32x4*)&pF[wid][l15][((g16 * 4 + lg) ^ l15) * 4] = pv;
    }

    // coalesced attn stores: instruction j covers rows j*4..j*4+3, 256 B/row contiguous
    #pragma unroll
    for (int j = 0; j < 4; ++j) {
      const int R = j * 4 + r2;
      f32x4 v = *(const f32x4*)&pF[wid][R][(c16 ^ R) * 4];
      *(f32x4*)(abase + (size_t)(qw + R) * S_LEN + kv0 + c16 * 4) = v;
    }

    // V(t) ready: younger ops = (2 next-K if pre) + 4 stores stay in flight
    if (pre) asm volatile("s_waitcnt vmcnt(6)" ::: "memory");
    else     asm volatile("s_waitcnt vmcnt(4)" ::: "memory");
    __builtin_amdgcn_s_barrier();

    // PV operands from pF: cols lg*8..+7 = granules 2lg,2lg+1; +32 = granules 8+2lg,9+2lg
    f32x4 alo = *(const f32x4*)&pF[wid][l15][((2 * lg) ^ l15) * 4];
    f32x4 ahi = *(const f32x4*)&pF[wid][l15][((2 * lg + 1) ^ l15) * 4];
    f32x4 blo = *(const f32x4*)&pF[wid][l15][((8 + 2 * lg) ^ l15) * 4];
    f32x4 bhi = *(const f32x4*)&pF[wid][l15][((9 + 2 * lg) ^ l15) * 4];
    short8_t pa0 = pack8(alo, ahi);
    short8_t pa1 = pack8(blo, bhi);
    #pragma unroll
    for (int dt = 0; dt < 4; ++dt) {
      const int r = dt * 16 + l15;
      short8_t bv0 = *(const short8_t*)(vS + r * 64 + ((lg ^ (r & 7)) * 8));
      short8_t bv1 = *(const short8_t*)(vS + r * 64 + (((4 + lg) ^ (r & 7)) * 8));
      ctx[dt] = __builtin_amdgcn_mfma_f32_16x16x32_bf16(bv0, pa0, ctx[dt], 0, 0, 0);
      ctx[dt] = __builtin_amdgcn_mfma_f32_16x16x32_bf16(bv1, pa1, ctx[dt], 0, 0, 0);
    }

    if (pre) {
      asm volatile("s_waitcnt vmcnt(4)" ::: "memory");
      __builtin_amdgcn_s_barrier();
    }
  }

  // ctx -> bf16 ctxb (coalesced u16x4): lane q = qrow, d = dt*16 + lg*4 + i
  #pragma unroll
  for (int dt = 0; dt < 4; ++dt) {
    u16x4 o;
    #pragma unroll
    for (int i = 0; i < 4; ++i) o[i] = f2bf(ctx[dt][i]);
    *(u16x4*)(ctxb + (size_t)(b * S_LEN + qrow) * HID_DIM + h * DHEAD + dt * 16 + lg * 4) = o;
  }
}

// ---------------------------------------------------------------- launch
extern "C" void kernel_launch(void* const* d_in, const int* in_sizes, int n_in,
                              void* d_out, int out_size, void* d_ws, size_t ws_size,
                              hipStream_t stream) {
  (void)in_sizes; (void)n_in; (void)out_size; (void)ws_size;
  const float* X    = (const float*)d_in[0];
  const float* cosb = (const float*)d_in[1];
  const float* sinb = (const float*)d_in[2];
  const float* Wq = (const float*)d_in[4];
  const float* bq = (const float*)d_in[5];
  const float* Wk = (const float*)d_in[6];
  const float* bk = (const float*)d_in[7];
  const float* Wv = (const float*)d_in[8];
  const float* bv = (const float*)d_in[9];
  const float* Wo = (const float*)d_in[10];
  const float* bo = (const float*)d_in[11];

  float* outp  = (float*)d_out;
  float* attnp = outp + (size_t)BATCH * S_LEN * HID_DIM;

  const int M = BATCH * S_LEN;           // 4096
  u16* ws    = (u16*)d_ws;
  u16* Xb    = ws;
  u16* Wqb   = Xb  + (size_t)M * HID_DIM;
  u16* Wkb   = Wqb + (size_t)HID_DIM * HID_DIM;
  u16* Wvb   = Wkb + (size_t)NKV * DHEAD * HID_DIM;
  u16* Wob   = Wvb + (size_t)NKV * DHEAD * HID_DIM;
  u16* qbuf  = Wob + (size_t)HID_DIM * HID_DIM;
  u16* kbuf  = qbuf + (size_t)M * HID_DIM;
  u16* vtbuf = kbuf + (size_t)M * NKV * DHEAD;     // [b][kvh][d][s] = (512, 2048)
  u16* ctxb  = vtbuf + (size_t)M * NKV * DHEAD;

  cast_all<<<dim3(1024, 5), 256, 0, stream>>>(X, Xb, Wq, Wqb, Wk, Wkb, Wv, Wvb, Wo, Wob);

  gemm_qkv<<<dim3(M / 64, 12), 256, 0, stream>>>(Xb, Wqb, Wkb, Wvb, bq, bk, bv,
                                                 cosb, sinb, qbuf, kbuf, vtbuf);

  attn_fused<<<dim3(BATCH * NHEAD, S_LEN / 64), 256, 0, stream>>>(qbuf, kbuf, vtbuf, attnp, ctxb);

  gemm_out<<<dim3(M / 64, HID_DIM / 128), 256, 0, stream>>>(ctxb, Wob, bo, outp);
}